// Round 21
// baseline (32.271 us; speedup 1.0000x reference)
//
#include <hip/hip_runtime.h>

// DividedModel: 64 towers of Dense(32,64)+ReLU -> 64x64+ReLU -> 64x64+ReLU -> 64x1.
// R20: R18-best structure (f16, prep-image + global_load_lds staging, pi-trick,
// bias-in-C, L3-as-MFMA, BPT=8 single-round, 4-tile ILP, x pre-converted, all
// weights in regs) with L1/L2 MFMA pairs DE-CHAINED: accA=MFMA(lo,bias),
// accB=MFMA(hi,0) issue independently; the sum folds into the pack stage as
// v_add before cvt. Shortens the per-tile dependency chain from 7 to 5 MFMA
// latencies at the cost of +16 VALU adds per tile-layer -- a discriminating
// test of the latency-stall hypothesis for the ~3300 cyc/iter no-issue gap.

typedef float  f32x4 __attribute__((ext_vector_type(4)));
typedef _Float16 h8  __attribute__((ext_vector_type(8)));
typedef unsigned int uint2v __attribute__((ext_vector_type(2)));
typedef unsigned int uint4v __attribute__((ext_vector_type(4)));

static constexpr int Bsz  = 16384;
static constexpr int Idim = 32;
static constexpr int Odim = 64;
static constexpr int BPT  = 8;                     // 512 blocks = one residency round
static constexpr int ROWTILES = (Bsz / 64) / BPT;  // 32 tiles of 64 rows per block
static constexpr int TT = 4;                       // tiles per iteration (ILP depth)

// per-tower LDS image layout (bytes):
//   [0,4096)      ushort Wt0[64*32]   Wt0[h*32 + (i^swz0)]
//   [4096,12288)  ushort Wt1[64*64]   Wt1[h*64 + (S^swz1)]
//   [12288,20480) ushort Wt2[64*64]
//   [20480,20608) ushort w3s[64]      w3s[S] = W3[o][in(S)]
//   [20608,21376) float  bs[192]      b0|b1|b2
//   [21376,21504) pad
static constexpr int IMG = 21504;                  // 21 chunks x 1024B
static constexpr int XH_OFF = 64 * IMG;            // f16 copy of x: 1 MB at ws+XH_OFF

#define GLD16(gp, lp) __builtin_amdgcn_global_load_lds( \
    (const __attribute__((address_space(1))) void*)(gp), \
    (__attribute__((address_space(3))) void*)(lp), 16, 0, 0)

__device__ __forceinline__ unsigned short f2h(float f) {   // RNE f32->f16 (staging)
    _Float16 h = (_Float16)f;
    return __builtin_bit_cast(unsigned short, h);
}

__device__ __forceinline__ unsigned cvt_relu_pk(float lo, float hi) {
    // pack 2 f32 -> 2 f16 (RTZ), then packed ReLU: one v_pk_max_f16
    unsigned v = __builtin_bit_cast(unsigned, __builtin_amdgcn_cvt_pkrtz(lo, hi));
    unsigned r;
    asm("v_pk_max_f16 %0, %1, 0" : "=v"(r) : "v"(v));
    return r;
}

// pi permutation: k-slot S for input-hidden index `in` (0..63).
// in_h(S) = 32*(S>>5) + 16*((S&7)>>2) + 4*((S>>3)&3) + (S&3).
__device__ __forceinline__ int pi_slot(int in) {
    return 32 * (in >> 5) + 8 * ((in >> 2) & 3) + 4 * ((in >> 4) & 1) + (in & 3);
}

// ---------------- prep: weight images + x f16 copy (chip-wide) ----------------
// blocks 0..255: weights (o = b>>2, quarter q = b&3); blocks 256..767: x convert.
__global__ __launch_bounds__(256) void prep_kernel(
    const float* __restrict__ x,
    const float* __restrict__ W0, const float* __restrict__ b0,
    const float* __restrict__ W1, const float* __restrict__ b1,
    const float* __restrict__ W2, const float* __restrict__ b2,
    const float* __restrict__ W3, char* __restrict__ ws)
{
    const int tid = threadIdx.x;
    if (blockIdx.x >= 256) {                 // ---- x: f32 -> f16, 1 f32x4/thread ----
        int idx = (blockIdx.x - 256) * 256 + tid;      // 0..131071 chunks of 4
        f32x4 v = *(const f32x4*)&x[idx * 4];
        uint2v d;
        d.x = (unsigned)f2h(v[0]) | ((unsigned)f2h(v[1]) << 16);
        d.y = (unsigned)f2h(v[2]) | ((unsigned)f2h(v[3]) << 16);
        *(uint2v*)(ws + XH_OFF + idx * 8) = d;
        return;
    }
    const int o = blockIdx.x >> 2, q = blockIdx.x & 3;
    char* img = ws + o * IMG;
    unsigned short* Wt0 = (unsigned short*)img;
    unsigned short* Wt1 = (unsigned short*)(img + 4096);
    unsigned short* Wt2 = (unsigned short*)(img + 12288);
    unsigned short* w3s = (unsigned short*)(img + 20480);
    float*          bsf = (float*)(img + 20608);

    {   // W1/W2: 1024 f32x4 chunks; this block handles q*256 + tid
        int f = q * 256 + tid;
        f32x4 v1 = *(const f32x4*)&W1[o * 4096 + f * 4];
        f32x4 v2 = *(const f32x4*)&W2[o * 4096 + f * 4];
        int in = (f * 4) >> 6;
        int h0 = (f * 4) & 63;
        int S  = pi_slot(in);
#pragma unroll
        for (int j = 0; j < 4; ++j) {
            int h = h0 + j;
            int cw = S ^ ((((h >> 2) ^ h) & 7) << 3);
            Wt1[h * 64 + cw] = f2h(v1[j]);
            Wt2[h * 64 + cw] = f2h(v2[j]);
        }
    }
    if (q < 2) {   // W0: 512 f32x4 chunks; blocks q=0,1
        int f = q * 256 + tid;
        f32x4 v = *(const f32x4*)&W0[o * 2048 + f * 4];
        int i  = (f * 4) >> 6;
        int h0 = (f * 4) & 63;
#pragma unroll
        for (int j = 0; j < 4; ++j) {
            int h = h0 + j;
            Wt0[h * 32 + (i ^ ((((h >> 2) ^ h) & 3) << 3))] = f2h(v[j]);
        }
    }
    if (q == 3 && tid < 64) {
        w3s[pi_slot(tid)] = f2h(W3[o * 64 + tid]);
        bsf[tid]       = b0[o * 64 + tid];
        bsf[64 + tid]  = b1[o * 64 + tid];
        bsf[128 + tid] = b2[o * 64 + tid];
    }
}

// ---------------- main: DMA-stage image, then 4-tile-ILP loop ----------------
__global__ __launch_bounds__(256, 2) void towers_kernel(
    const char* __restrict__ ws, const float* __restrict__ b3,
    float* __restrict__ out)
{
    __shared__ __align__(16) char SH[IMG];

    const int tid  = threadIdx.x;
    const int o    = blockIdx.x / BPT;
    const int slot = blockIdx.x % BPT;
    const int l = tid & 63, w = tid >> 6;
    const int c = l & 15,  g = l >> 4;   // c: batch col; g: k-group / D row-group

    // ---- first x prefetch BEFORE staging: overlaps with image DMA ----
    const _Float16* xh = (const _Float16*)(ws + XH_OFF);
    const _Float16* xbase = xh + (slot * ROWTILES * 64 + w * 16 + c) * Idim + g * 8;
    h8 nxv[TT];
#pragma unroll
    for (int k = 0; k < TT; ++k)
        nxv[k] = *(const h8*)(xbase + k * 2048);   // 64 rows x 32 = 2048 f16 per tile

    // ---- stage the tower image: 21 async 1KB chunks, waves round-robin ----
    {
        const char* img = ws + o * IMG;
#pragma unroll
        for (int ch = 0; ch < 6; ++ch) {
            int k = ch * 4 + w;
            if (k < 21)
                GLD16(img + k * 1024 + l * 16, SH + k * 1024);
        }
    }
    __syncthreads();

    const unsigned short* Wt0 = (const unsigned short*)SH;
    const unsigned short* Wt1 = (const unsigned short*)(SH + 4096);
    const unsigned short* Wt2 = (const unsigned short*)(SH + 12288);
    const unsigned short* w3s = (const unsigned short*)(SH + 20480);
    const float*          bsf = (const float*)(SH + 20608);

    // ---- persistent weight frags: W0 (16), W1 (32), W2 (32), w3 (8) ----
    h8 wf0[4], wf1f[4][2], wf2f[4][2];
#pragma unroll
    for (int n = 0; n < 4; ++n) {
        int h = n * 16 + c;
        wf0[n] = *(const h8*)&Wt0[h * 32 + ((g * 8) ^ ((((h >> 2) ^ h) & 3) << 3))];
        int key = ((h >> 2) ^ h) & 7;
#pragma unroll
        for (int s = 0; s < 2; ++s) {
            int col = (s * 32 + g * 8) ^ (key << 3);
            wf1f[n][s] = *(const h8*)&Wt1[h * 64 + col];
            wf2f[n][s] = *(const h8*)&Wt2[h * 64 + col];
        }
    }
    h8 w3a[2];
    w3a[0] = *(const h8*)&w3s[g * 8];
    w3a[1] = *(const h8*)&w3s[32 + g * 8];

    // ---- bias C-frags: element r of chunk n is hidden 16n+4g+r ----
    f32x4 b0f[4], b1f[4], b2f[4];
#pragma unroll
    for (int n = 0; n < 4; ++n) {
        b0f[n] = *(const f32x4*)&bsf[      n * 16 + g * 4];
        b1f[n] = *(const f32x4*)&bsf[ 64 + n * 16 + g * 4];
        b2f[n] = *(const f32x4*)&bsf[128 + n * 16 + g * 4];
    }
    f32x4 c3 = {0.f, 0.f, 0.f, 0.f};
    if (g == 0) c3[0] = b3[o];                // b3 lands on D row 0 only
    const f32x4 z4 = {0.f, 0.f, 0.f, 0.f};

    float* obase = out + (slot * ROWTILES * 64 + w * 16 + c) * Odim + o;

    for (int tt = 0; tt < ROWTILES; tt += TT) {
        h8 xv[TT];
#pragma unroll
        for (int k = 0; k < TT; ++k) xv[k] = nxv[k];
        if (tt + TT < ROWTILES) {             // prefetch next group
#pragma unroll
            for (int k = 0; k < TT; ++k)
                nxv[k] = *(const h8*)(xbase + (tt + TT + k) * 2048);
        }

        // ---- L0: x already f16 -> straight into MFMA ----
        f32x4 acc[TT][4];
#pragma unroll
        for (int n = 0; n < 4; ++n)
#pragma unroll
            for (int k = 0; k < TT; ++k)
                acc[k][n] = __builtin_amdgcn_mfma_f32_16x16x32_f16(wf0[n], xv[k], b0f[n], 0, 0, 0);

        // ---- cvt+relu pack (lane-local thanks to pi staging) ----
        h8 blo[TT], bhi[TT];
#pragma unroll
        for (int k = 0; k < TT; ++k) {
            uint4v lo, hi;
            lo.x = cvt_relu_pk(acc[k][0][0], acc[k][0][1]);
            lo.y = cvt_relu_pk(acc[k][0][2], acc[k][0][3]);
            lo.z = cvt_relu_pk(acc[k][1][0], acc[k][1][1]);
            lo.w = cvt_relu_pk(acc[k][1][2], acc[k][1][3]);
            hi.x = cvt_relu_pk(acc[k][2][0], acc[k][2][1]);
            hi.y = cvt_relu_pk(acc[k][2][2], acc[k][2][3]);
            hi.z = cvt_relu_pk(acc[k][3][0], acc[k][3][1]);
            hi.w = cvt_relu_pk(acc[k][3][2], acc[k][3][3]);
            blo[k] = __builtin_bit_cast(h8, lo);
            bhi[k] = __builtin_bit_cast(h8, hi);
        }

        // ---- L1: de-chained pair (accA has bias, accB has 0; sum in pack) ----
        f32x4 accB[TT][4];
#pragma unroll
        for (int n = 0; n < 4; ++n)
#pragma unroll
            for (int k = 0; k < TT; ++k) {
                acc[k][n]  = __builtin_amdgcn_mfma_f32_16x16x32_f16(wf1f[n][0], blo[k], b1f[n], 0, 0, 0);
                accB[k][n] = __builtin_amdgcn_mfma_f32_16x16x32_f16(wf1f[n][1], bhi[k], z4,     0, 0, 0);
            }
#pragma unroll
        for (int k = 0; k < TT; ++k) {
            f32x4 s0 = acc[k][0] + accB[k][0];
            f32x4 s1 = acc[k][1] + accB[k][1];
            f32x4 s2 = acc[k][2] + accB[k][2];
            f32x4 s3 = acc[k][3] + accB[k][3];
            uint4v lo, hi;
            lo.x = cvt_relu_pk(s0[0], s0[1]);
            lo.y = cvt_relu_pk(s0[2], s0[3]);
            lo.z = cvt_relu_pk(s1[0], s1[1]);
            lo.w = cvt_relu_pk(s1[2], s1[3]);
            hi.x = cvt_relu_pk(s2[0], s2[1]);
            hi.y = cvt_relu_pk(s2[2], s2[3]);
            hi.z = cvt_relu_pk(s3[0], s3[1]);
            hi.w = cvt_relu_pk(s3[2], s3[3]);
            blo[k] = __builtin_bit_cast(h8, lo);
            bhi[k] = __builtin_bit_cast(h8, hi);
        }

        // ---- L2: de-chained pair ----
#pragma unroll
        for (int n = 0; n < 4; ++n)
#pragma unroll
            for (int k = 0; k < TT; ++k) {
                acc[k][n]  = __builtin_amdgcn_mfma_f32_16x16x32_f16(wf2f[n][0], blo[k], b2f[n], 0, 0, 0);
                accB[k][n] = __builtin_amdgcn_mfma_f32_16x16x32_f16(wf2f[n][1], bhi[k], z4,     0, 0, 0);
            }
#pragma unroll
        for (int k = 0; k < TT; ++k) {
            f32x4 s0 = acc[k][0] + accB[k][0];
            f32x4 s1 = acc[k][1] + accB[k][1];
            f32x4 s2 = acc[k][2] + accB[k][2];
            f32x4 s3 = acc[k][3] + accB[k][3];
            uint4v lo, hi;
            lo.x = cvt_relu_pk(s0[0], s0[1]);
            lo.y = cvt_relu_pk(s0[2], s0[3]);
            lo.z = cvt_relu_pk(s1[0], s1[1]);
            lo.w = cvt_relu_pk(s1[2], s1[3]);
            hi.x = cvt_relu_pk(s2[0], s2[1]);
            hi.y = cvt_relu_pk(s2[2], s2[3]);
            hi.z = cvt_relu_pk(s3[0], s3[1]);
            hi.w = cvt_relu_pk(s3[2], s3[3]);
            blo[k] = __builtin_bit_cast(h8, lo);
            bhi[k] = __builtin_bit_cast(h8, hi);
        }

        // ---- L3: de-chained pair vs broadcast w3 rows; row 0 = dot + b3 ----
        f32x4 a3[TT], a3b[TT];
#pragma unroll
        for (int k = 0; k < TT; ++k) {
            a3[k]  = __builtin_amdgcn_mfma_f32_16x16x32_f16(w3a[0], blo[k], c3, 0, 0, 0);
            a3b[k] = __builtin_amdgcn_mfma_f32_16x16x32_f16(w3a[1], bhi[k], z4, 0, 0, 0);
        }
#pragma unroll
        for (int k = 0; k < TT; ++k)
            if (g == 0)
                obase[(tt + k) * 64 * Odim] = a3[k][0] + a3b[k][0];
    }
}

extern "C" void kernel_launch(void* const* d_in, const int* in_sizes, int n_in,
                              void* d_out, int out_size, void* d_ws, size_t ws_size,
                              hipStream_t stream) {
    const float* x  = (const float*)d_in[0];
    const float* W0 = (const float*)d_in[1];
    const float* b0 = (const float*)d_in[2];
    const float* W1 = (const float*)d_in[3];
    const float* b1 = (const float*)d_in[4];
    const float* W2 = (const float*)d_in[5];
    const float* b2 = (const float*)d_in[6];
    const float* W3 = (const float*)d_in[7];
    const float* b3 = (const float*)d_in[8];
    float* out = (float*)d_out;
    char* ws = (char*)d_ws;   // needs 64*21504 + 1MB = 2.43 MB

    prep_kernel<<<dim3(256 + 512), dim3(256), 0, stream>>>(x, W0, b0, W1, b1, W2, b2, W3, ws);
    towers_kernel<<<dim3(Odim * BPT), dim3(256), 0, stream>>>(ws, b3, out);
}

// Round 22
// 29.241 us; speedup vs baseline: 1.1036x; 1.1036x over previous
//
#include <hip/hip_runtime.h>

// DividedModel: 64 towers of Dense(32,64)+ReLU -> 64x64+ReLU -> 64x64+ReLU -> 64x1.
// FINAL (R18 = best measured, 29.28us): f16 MFMA, prep-kernel weight images +
// global_load_lds staging, pi-trick (k-slot permutation baked into weight
// staging makes inter-layer B-frags lane-local: zero cross-lane ops in loop),
// bias folded into MFMA C operand, L3 as 2 MFMAs vs broadcast w3 rows,
// BPT=8 single residency round, 4-tile ILP, x pre-converted to f16 in prep,
// all weights in registers (zero in-loop memory ops), setprio + startup skew.
// Plateau evidence: R14/R18/R19 = 29.4/29.3/29.7; occupancy pinned at
// ~2 waves/SIMD across all grid/bounds variants (R5/R8/R17 falsified);
// chain-shortening (R15/R20) and sched-freedom (R19) regress/null.

typedef float  f32x4 __attribute__((ext_vector_type(4)));
typedef _Float16 h8  __attribute__((ext_vector_type(8)));
typedef unsigned int uint2v __attribute__((ext_vector_type(2)));
typedef unsigned int uint4v __attribute__((ext_vector_type(4)));

static constexpr int Bsz  = 16384;
static constexpr int Idim = 32;
static constexpr int Odim = 64;
static constexpr int BPT  = 8;                     // 512 blocks = one residency round
static constexpr int ROWTILES = (Bsz / 64) / BPT;  // 32 tiles of 64 rows per block
static constexpr int TT = 4;                       // tiles per iteration (ILP depth)

// per-tower LDS image layout (bytes):
//   [0,4096)      ushort Wt0[64*32]   Wt0[h*32 + (i^swz0)]
//   [4096,12288)  ushort Wt1[64*64]   Wt1[h*64 + (S^swz1)]
//   [12288,20480) ushort Wt2[64*64]
//   [20480,20608) ushort w3s[64]      w3s[S] = W3[o][in(S)]
//   [20608,21376) float  bs[192]      b0|b1|b2
//   [21376,21504) pad
static constexpr int IMG = 21504;                  // 21 chunks x 1024B
static constexpr int XH_OFF = 64 * IMG;            // f16 copy of x: 1 MB at ws+XH_OFF

#define GLD16(gp, lp) __builtin_amdgcn_global_load_lds( \
    (const __attribute__((address_space(1))) void*)(gp), \
    (__attribute__((address_space(3))) void*)(lp), 16, 0, 0)

__device__ __forceinline__ unsigned short f2h(float f) {   // RNE f32->f16 (staging)
    _Float16 h = (_Float16)f;
    return __builtin_bit_cast(unsigned short, h);
}

__device__ __forceinline__ unsigned cvt_relu_pk(float lo, float hi) {
    // pack 2 f32 -> 2 f16 (RTZ), then packed ReLU: one v_pk_max_f16
    unsigned v = __builtin_bit_cast(unsigned, __builtin_amdgcn_cvt_pkrtz(lo, hi));
    unsigned r;
    asm("v_pk_max_f16 %0, %1, 0" : "=v"(r) : "v"(v));
    return r;
}

// pi permutation: k-slot S for input-hidden index `in` (0..63).
// in_h(S) = 32*(S>>5) + 16*((S&7)>>2) + 4*((S>>3)&3) + (S&3).
__device__ __forceinline__ int pi_slot(int in) {
    return 32 * (in >> 5) + 8 * ((in >> 2) & 3) + 4 * ((in >> 4) & 1) + (in & 3);
}

// ---------------- prep: weight images + x f16 copy (chip-wide) ----------------
// blocks 0..255: weights (o = b>>2, quarter q = b&3); blocks 256..767: x convert.
__global__ __launch_bounds__(256) void prep_kernel(
    const float* __restrict__ x,
    const float* __restrict__ W0, const float* __restrict__ b0,
    const float* __restrict__ W1, const float* __restrict__ b1,
    const float* __restrict__ W2, const float* __restrict__ b2,
    const float* __restrict__ W3, char* __restrict__ ws)
{
    const int tid = threadIdx.x;
    if (blockIdx.x >= 256) {                 // ---- x: f32 -> f16, 1 f32x4/thread ----
        int idx = (blockIdx.x - 256) * 256 + tid;      // 0..131071 chunks of 4
        f32x4 v = *(const f32x4*)&x[idx * 4];
        uint2v d;
        d.x = (unsigned)f2h(v[0]) | ((unsigned)f2h(v[1]) << 16);
        d.y = (unsigned)f2h(v[2]) | ((unsigned)f2h(v[3]) << 16);
        *(uint2v*)(ws + XH_OFF + idx * 8) = d;
        return;
    }
    const int o = blockIdx.x >> 2, q = blockIdx.x & 3;
    char* img = ws + o * IMG;
    unsigned short* Wt0 = (unsigned short*)img;
    unsigned short* Wt1 = (unsigned short*)(img + 4096);
    unsigned short* Wt2 = (unsigned short*)(img + 12288);
    unsigned short* w3s = (unsigned short*)(img + 20480);
    float*          bsf = (float*)(img + 20608);

    {   // W1/W2: 1024 f32x4 chunks; this block handles q*256 + tid
        int f = q * 256 + tid;
        f32x4 v1 = *(const f32x4*)&W1[o * 4096 + f * 4];
        f32x4 v2 = *(const f32x4*)&W2[o * 4096 + f * 4];
        int in = (f * 4) >> 6;
        int h0 = (f * 4) & 63;
        int S  = pi_slot(in);
#pragma unroll
        for (int j = 0; j < 4; ++j) {
            int h = h0 + j;
            int cw = S ^ ((((h >> 2) ^ h) & 7) << 3);
            Wt1[h * 64 + cw] = f2h(v1[j]);
            Wt2[h * 64 + cw] = f2h(v2[j]);
        }
    }
    if (q < 2) {   // W0: 512 f32x4 chunks; blocks q=0,1
        int f = q * 256 + tid;
        f32x4 v = *(const f32x4*)&W0[o * 2048 + f * 4];
        int i  = (f * 4) >> 6;
        int h0 = (f * 4) & 63;
#pragma unroll
        for (int j = 0; j < 4; ++j) {
            int h = h0 + j;
            Wt0[h * 32 + (i ^ ((((h >> 2) ^ h) & 3) << 3))] = f2h(v[j]);
        }
    }
    if (q == 3 && tid < 64) {
        w3s[pi_slot(tid)] = f2h(W3[o * 64 + tid]);
        bsf[tid]       = b0[o * 64 + tid];
        bsf[64 + tid]  = b1[o * 64 + tid];
        bsf[128 + tid] = b2[o * 64 + tid];
    }
}

// ---------------- main: DMA-stage image, then 4-tile-ILP loop ----------------
__global__ __launch_bounds__(256, 2) void towers_kernel(
    const char* __restrict__ ws, const float* __restrict__ b3,
    float* __restrict__ out)
{
    __shared__ __align__(16) char SH[IMG];

    const int tid  = threadIdx.x;
    const int o    = blockIdx.x / BPT;
    const int slot = blockIdx.x % BPT;
    const int l = tid & 63, w = tid >> 6;
    const int c = l & 15,  g = l >> 4;   // c: batch col; g: k-group / D row-group

    // ---- first x prefetch BEFORE staging: overlaps with image DMA ----
    const _Float16* xh = (const _Float16*)(ws + XH_OFF);
    const _Float16* xbase = xh + (slot * ROWTILES * 64 + w * 16 + c) * Idim + g * 8;
    h8 nxv[TT];
#pragma unroll
    for (int k = 0; k < TT; ++k)
        nxv[k] = *(const h8*)(xbase + k * 2048);   // 64 rows x 32 = 2048 f16 per tile

    // ---- stage the tower image: 21 async 1KB chunks, waves round-robin ----
    {
        const char* img = ws + o * IMG;
#pragma unroll
        for (int ch = 0; ch < 6; ++ch) {
            int k = ch * 4 + w;
            if (k < 21)
                GLD16(img + k * 1024 + l * 16, SH + k * 1024);
        }
    }
    __syncthreads();

    const unsigned short* Wt0 = (const unsigned short*)SH;
    const unsigned short* Wt1 = (const unsigned short*)(SH + 4096);
    const unsigned short* Wt2 = (const unsigned short*)(SH + 12288);
    const unsigned short* w3s = (const unsigned short*)(SH + 20480);
    const float*          bsf = (const float*)(SH + 20608);

    // ---- persistent weight frags: W0 (16), W1 (32), W2 (32), w3 (8) ----
    h8 wf0[4], wf1f[4][2], wf2f[4][2];
#pragma unroll
    for (int n = 0; n < 4; ++n) {
        int h = n * 16 + c;
        wf0[n] = *(const h8*)&Wt0[h * 32 + ((g * 8) ^ ((((h >> 2) ^ h) & 3) << 3))];
        int key = ((h >> 2) ^ h) & 7;
#pragma unroll
        for (int s = 0; s < 2; ++s) {
            int col = (s * 32 + g * 8) ^ (key << 3);
            wf1f[n][s] = *(const h8*)&Wt1[h * 64 + col];
            wf2f[n][s] = *(const h8*)&Wt2[h * 64 + col];
        }
    }
    h8 w3a[2];
    w3a[0] = *(const h8*)&w3s[g * 8];
    w3a[1] = *(const h8*)&w3s[32 + g * 8];

    // ---- bias C-frags: element r of chunk n is hidden 16n+4g+r ----
    f32x4 b0f[4], b1f[4], b2f[4];
#pragma unroll
    for (int n = 0; n < 4; ++n) {
        b0f[n] = *(const f32x4*)&bsf[      n * 16 + g * 4];
        b1f[n] = *(const f32x4*)&bsf[ 64 + n * 16 + g * 4];
        b2f[n] = *(const f32x4*)&bsf[128 + n * 16 + g * 4];
    }
    f32x4 c3 = {0.f, 0.f, 0.f, 0.f};
    if (g == 0) c3[0] = b3[o];                // b3 lands on D row 0 only

    float* obase = out + (slot * ROWTILES * 64 + w * 16 + c) * Odim + o;

    // ---- startup skew: de-phase co-resident waves (one-time, <=768 cyc) ----
    {
        int skew = (int)((blockIdx.x * 3 + w) & 3);
        if (skew == 1)      __builtin_amdgcn_s_sleep(4);   // ~256 cyc
        else if (skew == 2) __builtin_amdgcn_s_sleep(8);   // ~512 cyc
        else if (skew == 3) __builtin_amdgcn_s_sleep(12);  // ~768 cyc
    }

    for (int tt = 0; tt < ROWTILES; tt += TT) {
        h8 xv[TT];
#pragma unroll
        for (int k = 0; k < TT; ++k) xv[k] = nxv[k];
        if (tt + TT < ROWTILES) {             // prefetch next group
#pragma unroll
            for (int k = 0; k < TT; ++k)
                nxv[k] = *(const h8*)(xbase + (tt + TT + k) * 2048);
        }

        // ---- L0: x already f16 -> straight into MFMA ----
        f32x4 acc[TT][4];
        __builtin_amdgcn_s_setprio(1);
#pragma unroll
        for (int n = 0; n < 4; ++n)
#pragma unroll
            for (int k = 0; k < TT; ++k)
                acc[k][n] = __builtin_amdgcn_mfma_f32_16x16x32_f16(wf0[n], xv[k], b0f[n], 0, 0, 0);
        __builtin_amdgcn_s_setprio(0);

        // ---- cvt+relu pack (lane-local thanks to pi staging) ----
        h8 blo[TT], bhi[TT];
#pragma unroll
        for (int k = 0; k < TT; ++k) {
            uint4v lo, hi;
            lo.x = cvt_relu_pk(acc[k][0][0], acc[k][0][1]);
            lo.y = cvt_relu_pk(acc[k][0][2], acc[k][0][3]);
            lo.z = cvt_relu_pk(acc[k][1][0], acc[k][1][1]);
            lo.w = cvt_relu_pk(acc[k][1][2], acc[k][1][3]);
            hi.x = cvt_relu_pk(acc[k][2][0], acc[k][2][1]);
            hi.y = cvt_relu_pk(acc[k][2][2], acc[k][2][3]);
            hi.z = cvt_relu_pk(acc[k][3][0], acc[k][3][1]);
            hi.w = cvt_relu_pk(acc[k][3][2], acc[k][3][3]);
            blo[k] = __builtin_bit_cast(h8, lo);
            bhi[k] = __builtin_bit_cast(h8, hi);
        }

        // ---- L1 ----
        __builtin_amdgcn_s_setprio(1);
#pragma unroll
        for (int n = 0; n < 4; ++n)
#pragma unroll
            for (int k = 0; k < TT; ++k) {
                acc[k][n] = __builtin_amdgcn_mfma_f32_16x16x32_f16(wf1f[n][0], blo[k], b1f[n], 0, 0, 0);
                acc[k][n] = __builtin_amdgcn_mfma_f32_16x16x32_f16(wf1f[n][1], bhi[k], acc[k][n], 0, 0, 0);
            }
        __builtin_amdgcn_s_setprio(0);
#pragma unroll
        for (int k = 0; k < TT; ++k) {
            uint4v lo, hi;
            lo.x = cvt_relu_pk(acc[k][0][0], acc[k][0][1]);
            lo.y = cvt_relu_pk(acc[k][0][2], acc[k][0][3]);
            lo.z = cvt_relu_pk(acc[k][1][0], acc[k][1][1]);
            lo.w = cvt_relu_pk(acc[k][1][2], acc[k][1][3]);
            hi.x = cvt_relu_pk(acc[k][2][0], acc[k][2][1]);
            hi.y = cvt_relu_pk(acc[k][2][2], acc[k][2][3]);
            hi.z = cvt_relu_pk(acc[k][3][0], acc[k][3][1]);
            hi.w = cvt_relu_pk(acc[k][3][2], acc[k][3][3]);
            blo[k] = __builtin_bit_cast(h8, lo);
            bhi[k] = __builtin_bit_cast(h8, hi);
        }

        // ---- L2 (weights in regs -- zero memory ops in loop) ----
        __builtin_amdgcn_s_setprio(1);
#pragma unroll
        for (int n = 0; n < 4; ++n)
#pragma unroll
            for (int k = 0; k < TT; ++k) {
                acc[k][n] = __builtin_amdgcn_mfma_f32_16x16x32_f16(wf2f[n][0], blo[k], b2f[n], 0, 0, 0);
                acc[k][n] = __builtin_amdgcn_mfma_f32_16x16x32_f16(wf2f[n][1], bhi[k], acc[k][n], 0, 0, 0);
            }
        __builtin_amdgcn_s_setprio(0);
#pragma unroll
        for (int k = 0; k < TT; ++k) {
            uint4v lo, hi;
            lo.x = cvt_relu_pk(acc[k][0][0], acc[k][0][1]);
            lo.y = cvt_relu_pk(acc[k][0][2], acc[k][0][3]);
            lo.z = cvt_relu_pk(acc[k][1][0], acc[k][1][1]);
            lo.w = cvt_relu_pk(acc[k][1][2], acc[k][1][3]);
            hi.x = cvt_relu_pk(acc[k][2][0], acc[k][2][1]);
            hi.y = cvt_relu_pk(acc[k][2][2], acc[k][2][3]);
            hi.z = cvt_relu_pk(acc[k][3][0], acc[k][3][1]);
            hi.w = cvt_relu_pk(acc[k][3][2], acc[k][3][3]);
            blo[k] = __builtin_bit_cast(h8, lo);
            bhi[k] = __builtin_bit_cast(h8, hi);
        }

        // ---- L3: 2 chained MFMAs per tile vs broadcast w3 rows; row 0 = dot + b3 ----
        __builtin_amdgcn_s_setprio(1);
        f32x4 a3[TT];
#pragma unroll
        for (int k = 0; k < TT; ++k) {
            a3[k] = __builtin_amdgcn_mfma_f32_16x16x32_f16(w3a[0], blo[k], c3, 0, 0, 0);
            a3[k] = __builtin_amdgcn_mfma_f32_16x16x32_f16(w3a[1], bhi[k], a3[k], 0, 0, 0);
        }
        __builtin_amdgcn_s_setprio(0);
#pragma unroll
        for (int k = 0; k < TT; ++k)
            if (g == 0)
                obase[(tt + k) * 64 * Odim] = a3[k][0];
    }
}

extern "C" void kernel_launch(void* const* d_in, const int* in_sizes, int n_in,
                              void* d_out, int out_size, void* d_ws, size_t ws_size,
                              hipStream_t stream) {
    const float* x  = (const float*)d_in[0];
    const float* W0 = (const float*)d_in[1];
    const float* b0 = (const float*)d_in[2];
    const float* W1 = (const float*)d_in[3];
    const float* b1 = (const float*)d_in[4];
    const float* W2 = (const float*)d_in[5];
    const float* b2 = (const float*)d_in[6];
    const float* W3 = (const float*)d_in[7];
    const float* b3 = (const float*)d_in[8];
    float* out = (float*)d_out;
    char* ws = (char*)d_ws;   // needs 64*21504 + 1MB = 2.43 MB

    prep_kernel<<<dim3(256 + 512), dim3(256), 0, stream>>>(x, W0, b0, W1, b1, W2, b2, W3, ws);
    towers_kernel<<<dim3(Odim * BPT), dim3(256), 0, stream>>>(ws, b3, out);
}